// Round 1
// baseline (515.830 us; speedup 1.0000x reference)
//
#include <hip/hip_runtime.h>
#include <hip/hip_bf16.h>
#include <math.h>

typedef float floatx4 __attribute__((ext_vector_type(4)));
typedef __bf16 bf16x8 __attribute__((ext_vector_type(8)));
typedef unsigned short ushort_t;

__device__ __forceinline__ ushort_t f2bf(float f) {
    union { float f; unsigned int i; } v; v.f = f;
    unsigned int i = v.i;
    return (ushort_t)((i + 0x7FFFu + ((i >> 16) & 1u)) >> 16);  // RNE, inputs finite
}
__device__ __forceinline__ unsigned int pack2(float a, float b) {
    return (unsigned int)f2bf(a) | ((unsigned int)f2bf(b) << 16);
}
__device__ __forceinline__ floatx4 mfma16(bf16x8 a, bf16x8 b, floatx4 c) {
    return __builtin_amdgcn_mfma_f32_16x16x32_bf16(a, b, c, 0, 0, 0);
}
// async global->LDS, 16B/lane; g is PER-LANE address, lds base wave-uniform,
// lane i lands at lds_base + i*16 bytes
__device__ __forceinline__ void load_lds16(const ushort_t* g, ushort_t* l) {
    __builtin_amdgcn_global_load_lds(
        (const __attribute__((address_space(1))) unsigned int*)g,
        (__attribute__((address_space(3))) unsigned int*)l, 16, 0, 0);
}

// ---------------- fp32 -> bf16 conversion of activations (q,k,v,loc), 3200x2048 each
__global__ __launch_bounds__(256) void k_convert(const float* __restrict__ q, const float* __restrict__ k,
                          const float* __restrict__ v, const float* __restrict__ loc,
                          ushort_t* qb, ushort_t* kb, ushort_t* vb, ushort_t* locb) {
    int z = blockIdx.y;
    const float* src = z == 0 ? q : z == 1 ? k : z == 2 ? v : loc;
    ushort_t* dst    = z == 0 ? qb : z == 1 ? kb : z == 2 ? vb : locb;
    size_t idx = (size_t)blockIdx.x * 256 + threadIdx.x;
    floatx4 f = *(const floatx4*)(src + idx * 4);
    uint2 o;
    o.x = pack2(f[0], f[1]);
    o.y = pack2(f[2], f[3]);
    *(uint2*)(dst + idx * 4) = o;
}

// ---------------- Weight transpose+convert: W (2048x2048 fp32, KxN) -> Wt (NxK bf16)
__global__ void k_wtrans(const float* __restrict__ w0, const float* __restrict__ w1,
                         const float* __restrict__ w2, const float* __restrict__ w3,
                         const float* __restrict__ w4,
                         ushort_t* t0, ushort_t* t1, ushort_t* t2, ushort_t* t3, ushort_t* t4) {
    __shared__ float tile[32][33];
    int z = blockIdx.z;
    const float* W = z == 0 ? w0 : z == 1 ? w1 : z == 2 ? w2 : z == 3 ? w3 : w4;
    ushort_t* T    = z == 0 ? t0 : z == 1 ? t1 : z == 2 ? t2 : z == 3 ? t3 : t4;
    int n0 = blockIdx.x * 32, k0 = blockIdx.y * 32;
    int tx = threadIdx.x & 31, ty = threadIdx.x >> 5;
#pragma unroll
    for (int i = 0; i < 4; i++) {
        int row = ty + i * 8;
        tile[row][tx] = W[(size_t)(k0 + row) * 2048 + n0 + tx];
    }
    __syncthreads();
#pragma unroll
    for (int i = 0; i < 4; i++) {
        int row = ty + i * 8;
        T[(size_t)(n0 + row) * 2048 + k0 + tx] = f2bf(tile[tx][row]);
    }
}

// ---------------- lv (3200x2048 bf16) -> lvT ([b][h][t] padded t->224, zeros)
__global__ void k_vtrans(const ushort_t* __restrict__ lv, ushort_t* __restrict__ lvT) {
    __shared__ ushort_t tile[32][33];
    int n0 = blockIdx.x * 32;
    int t0 = blockIdx.y * 32;
    int b = blockIdx.z;
    int tx = threadIdx.x & 31, ty = threadIdx.x >> 5;
#pragma unroll
    for (int i = 0; i < 4; i++) {
        int row = ty + i * 8;
        int tk = t0 + row;
        ushort_t v = 0;
        if (tk < 200) v = lv[(size_t)(b * 200 + tk) * 2048 + n0 + tx];
        tile[row][tx] = v;
    }
    __syncthreads();
#pragma unroll
    for (int i = 0; i < 4; i++) {
        int row = ty + i * 8;
        lvT[((size_t)b * 2048 + n0 + row) * 224 + t0 + tx] = tile[tx][row];
    }
}

// ---------------- Batched projection GEMM, 256x256 tile, BK=32 double-buffered,
// counted vmcnt (never drains in main loop), swizzled LDS (conflict-free ds_read_b128),
// XCD-aware block swizzle. 512 threads = 8 waves (2 M x 4 N), per-wave 128x64 output.
// z=0 -> lqp, z=1 -> kcat[:, 0:2048], z=2 -> lvp, z=3 -> llocp, z=4 -> kcat[:, 2048:4096]
#define G_SB  __builtin_amdgcn_sched_barrier(0)
#define G_BAR __builtin_amdgcn_s_barrier()

__global__ __launch_bounds__(512, 2) void k_gemm(
    const ushort_t* A0, const ushort_t* A1, const ushort_t* A2, const ushort_t* A3, const ushort_t* A4,
    const ushort_t* W0, const ushort_t* W1, const ushort_t* W2, const ushort_t* W3, const ushort_t* W4,
    const float* B0, const float* B1, const float* B2, const float* B3, const float* B4,
    ushort_t* lqp, ushort_t* lvp, ushort_t* llocp, ushort_t* kcat) {
    // 520 workgroups = 8 XCDs x 65; bijective XCD swizzle (nwg % 8 == 0)
    int wg = blockIdx.x;
    int swz = (wg & 7) * 65 + (wg >> 3);
    int z = swz / 104;                 // 13 m-tiles x 8 n-tiles = 104 per z
    int rem = swz - z * 104;
    int ntile = rem / 13;              // column-major: consecutive blocks share B-panel
    int mtile = rem - ntile * 13;
    int m0 = mtile * 256, n0 = ntile * 256;

    const ushort_t* A  = z == 0 ? A0 : z == 1 ? A1 : z == 2 ? A2 : z == 3 ? A3 : A4;
    const ushort_t* Wt = z == 0 ? W0 : z == 1 ? W1 : z == 2 ? W2 : z == 3 ? W3 : W4;
    const float* bias  = z == 0 ? B0 : z == 1 ? B1 : z == 2 ? B2 : z == 3 ? B3 : B4;

    __shared__ ushort_t As[2][256 * 32];   // 16 KB each
    __shared__ ushort_t Bs[2][256 * 32];

    int tid = threadIdx.x;
    int lane = tid & 63, w = tid >> 6;
    int quad = lane >> 4, col = lane & 15;
    int wr = w >> 2, wc = w & 3;

    // --- staging addresses. Each global_load_lds covers 16 rows x 64 B (one wave, 1 KB).
    // LDS is written linearly (lane*16B); the XOR swizzle (chunk ^= (row>>1)&3) is applied
    // on the GLOBAL source address so LDS slot (row, c) holds element chunk c ^ ((row>>1)&3).
    int srow = lane >> 2;                          // row within 16-row slab
    int cch  = (lane & 3) ^ ((lane >> 3) & 3);     // pre-swizzled 16B chunk
    const ushort_t* AgB0 = A  + (size_t)(m0 + (0 * 8 + w) * 16 + srow) * 2048 + cch * 8;
    const ushort_t* AgB1 = A  + (size_t)(m0 + (1 * 8 + w) * 16 + srow) * 2048 + cch * 8;
    const ushort_t* BgB0 = Wt + (size_t)(n0 + (0 * 8 + w) * 16 + srow) * 2048 + cch * 8;
    const ushort_t* BgB1 = Wt + (size_t)(n0 + (1 * 8 + w) * 16 + srow) * 2048 + cch * 8;
    int dst0 = (0 * 8 + w) * 512;   // ushort offset of the 1 KB slab
    int dst1 = (1 * 8 + w) * 512;

#define G_STAGE(K0, B) do {                         \
        load_lds16(AgB0 + (K0), As[B] + dst0);      \
        load_lds16(AgB1 + (K0), As[B] + dst1);      \
        load_lds16(BgB0 + (K0), Bs[B] + dst0);      \
        load_lds16(BgB1 + (K0), Bs[B] + dst1);      \
    } while (0)

    // --- fragment read offsets (swizzled): byte = row*64 + (quad ^ ((row>>1)&3))*16
    int aoff[8], boff[4];
#pragma unroll
    for (int mi = 0; mi < 8; mi++) {
        int row = wr * 128 + mi * 16 + col;
        aoff[mi] = row * 32 + (quad ^ ((row >> 1) & 3)) * 8;
    }
#pragma unroll
    for (int ni = 0; ni < 4; ni++) {
        int row = wc * 64 + ni * 16 + col;
        boff[ni] = row * 32 + (quad ^ ((row >> 1) & 3)) * 8;
    }

    floatx4 acc[8][4] = {};

#define G_COMPUTE(B) do {                                                \
        bf16x8 af[8], bfr[4];                                            \
        _Pragma("unroll") for (int mi = 0; mi < 8; mi++)                 \
            af[mi] = *(const bf16x8*)&As[B][aoff[mi]];                   \
        _Pragma("unroll") for (int ni = 0; ni < 4; ni++)                 \
            bfr[ni] = *(const bf16x8*)&Bs[B][boff[ni]];                  \
        __builtin_amdgcn_s_setprio(1);                                   \
        _Pragma("unroll") for (int mi = 0; mi < 8; mi++)                 \
            _Pragma("unroll") for (int ni = 0; ni < 4; ni++)             \
                acc[mi][ni] = mfma16(af[mi], bfr[ni], acc[mi][ni]);      \
        __builtin_amdgcn_s_setprio(0);                                   \
    } while (0)

    // prologue: stage K-tile 0 into buf 0 (4 loads in flight)
    G_STAGE(0, 0);

    // main loop: K = 2048 -> 64 K-tiles of 32; process pairs (buf0, buf1).
    // Invariant at each stage point: the buffer being overwritten was last read
    // before the previous barrier; vmcnt(4) retires exactly the current tile's loads
    // while the next tile's 4 stay in flight across the barrier (counted, never drained).
#pragma unroll 1
    for (int tt = 0; tt < 31; tt++) {
        int k0 = tt * 64;
        G_STAGE(k0 + 32, 1);
        asm volatile("s_waitcnt vmcnt(4)" ::: "memory");
        G_SB; G_BAR; G_SB;
        G_COMPUTE(0);
        G_SB; G_BAR;
        G_STAGE(k0 + 64, 0);
        asm volatile("s_waitcnt vmcnt(4)" ::: "memory");
        G_SB; G_BAR; G_SB;
        G_COMPUTE(1);
        G_SB; G_BAR;
    }
    // t = 62 (buf0), stage tile 63 -> buf1
    G_STAGE(2016, 1);
    asm volatile("s_waitcnt vmcnt(4)" ::: "memory");
    G_SB; G_BAR; G_SB;
    G_COMPUTE(0);
    G_SB; G_BAR;
    // t = 63 (buf1), final tile: full drain
    asm volatile("s_waitcnt vmcnt(0)" ::: "memory");
    G_SB; G_BAR; G_SB;
    G_COMPUTE(1);

    // --- epilogue: bias add, bf16 convert, store (rows >= 3200 are padding -> guarded)
    ushort_t* Cplain = z == 0 ? lqp : z == 2 ? lvp : llocp;
    int kcoff = (z == 4) ? 2048 : 0;
    bool to_kcat = (z == 1 || z == 4);
    float bvv[4];
#pragma unroll
    for (int ni = 0; ni < 4; ni++) bvv[ni] = bias[n0 + wc * 64 + ni * 16 + col];
#pragma unroll
    for (int mi = 0; mi < 8; mi++) {
#pragma unroll
        for (int r = 0; r < 4; r++) {
            int m = m0 + wr * 128 + mi * 16 + quad * 4 + r;
            if (m < 3200) {
                ushort_t* crow;
                if (to_kcat) {
                    int bb = m / 200, rr = m - bb * 200;
                    crow = kcat + (size_t)(bb * 224 + rr) * 4096 + kcoff;
                } else {
                    crow = Cplain + (size_t)m * 2048;
                }
#pragma unroll
                for (int ni = 0; ni < 4; ni++) {
                    int n = n0 + wc * 64 + ni * 16 + col;
                    crow[n] = f2bf(acc[mi][ni][r] + bvv[ni]);
                }
            }
        }
    }
#undef G_STAGE
#undef G_COMPUTE
}

// ---------------- qcat[b][r][0:2048] = lq + param ; qcat[b][r][2048:] = lq + lloc
__global__ __launch_bounds__(256) void k_qprep(const ushort_t* __restrict__ lqp,
                                               const ushort_t* __restrict__ llocp,
                                               const float* __restrict__ param,
                                               ushort_t* __restrict__ qcat) {
    int m = blockIdx.x;           // 0..3199
    int b = m / 200, r = m - b * 200;
    int c = threadIdx.x * 8;
    bf16x8 ql = *(const bf16x8*)(lqp + (size_t)m * 2048 + c);
    bf16x8 ll = *(const bf16x8*)(llocp + (size_t)m * 2048 + c);
    floatx4 p0 = *(const floatx4*)(param + (size_t)m * 2048 + c);
    floatx4 p1 = *(const floatx4*)(param + (size_t)m * 2048 + c + 4);
    bf16x8 q1, q2;
#pragma unroll
    for (int j = 0; j < 4; j++) {
        q1[j]     = (__bf16)((float)ql[j] + p0[j]);
        q1[j + 4] = (__bf16)((float)ql[j + 4] + p1[j]);
        q2[j]     = (__bf16)((float)ql[j] + (float)ll[j]);
        q2[j + 4] = (__bf16)((float)ql[j + 4] + (float)ll[j + 4]);
    }
    ushort_t* dst = qcat + ((size_t)(b * 224 + r)) * 4096 + c;
    *(bf16x8*)dst = q1;
    *(bf16x8*)(dst + 2048) = q2;
}

// ---------------- Scores (K-split): part[kc][b][row 0..223][key 0..223] fp32 partial
// grid (7 qt x 16 b x 2 kc), 256 thr; 32 q-rows x 224 keys, K=2048 per block
__global__ __launch_bounds__(256) void k_scores(const ushort_t* __restrict__ qcat,
                                                const ushort_t* __restrict__ kcat,
                                                float* __restrict__ part) {
    int qt = blockIdx.x;   // 0..6
    int b  = blockIdx.y;   // 0..15
    int kc = blockIdx.z;   // 0..1
    __shared__ ushort_t As[32 * 32];    // 2 KB
    __shared__ ushort_t Bs[224 * 32];   // 14 KB

    int tid = threadIdx.x;
    int lane = tid & 63, w = tid >> 6;
    int quad = lane >> 4, col = lane & 15;
    int srow = lane >> 2, scol = (lane & 3) * 8;

    const ushort_t* qbase = qcat + ((size_t)b * 224 + qt * 32) * 4096 + kc * 2048;
    const ushort_t* kbase = kcat + (size_t)b * 224 * 4096 + kc * 2048;

    const ushort_t* ssrc[4];
    ushort_t* sdst[4];
#pragma unroll
    for (int o = 0; o < 4; o++) {
        int id = w * 4 + o;
        if (id < 14) {
            ssrc[o] = kbase + (size_t)(id * 16 + srow) * 4096 + scol;
            sdst[o] = Bs + id * 512;
        } else {
            ssrc[o] = qbase + (size_t)((id - 14) * 16 + srow) * 4096 + scol;
            sdst[o] = As + (id - 14) * 512;
        }
    }

    floatx4 acc[2][4] = {};
    for (int k0 = 0; k0 < 2048; k0 += 32) {
        __syncthreads();
#pragma unroll
        for (int o = 0; o < 4; o++) load_lds16(ssrc[o] + k0, sdst[o]);
        __syncthreads();
        bf16x8 af[2];
#pragma unroll
        for (int mi = 0; mi < 2; mi++) af[mi] = *(const bf16x8*)&As[(mi * 16 + col) * 32 + quad * 8];
#pragma unroll
        for (int fi = 0; fi < 4; fi++) {
            int f = w + fi * 4;
            if (f < 14) {
                bf16x8 bf = *(const bf16x8*)&Bs[(f * 16 + col) * 32 + quad * 8];
#pragma unroll
                for (int mi = 0; mi < 2; mi++) acc[mi][fi] = mfma16(af[mi], bf, acc[mi][fi]);
            }
        }
    }

    float* pbase = part + ((size_t)(kc * 16 + b) * 224 + qt * 32) * 224;
#pragma unroll
    for (int fi = 0; fi < 4; fi++) {
        int f = w + fi * 4;
        if (f < 14) {
#pragma unroll
            for (int mi = 0; mi < 2; mi++)
#pragma unroll
                for (int r = 0; r < 4; r++)
                    pbase[(mi * 16 + quad * 4 + r) * 224 + f * 16 + col] = acc[mi][fi][r];
        }
    }
}

// ---------------- softmax over summed partials -> attn bf16 [b][200][224], cols>=200 zero
// grid 400 blocks x 256 thr; 8 rows/block, 32 threads/row, 7 cols/thread
__global__ __launch_bounds__(256) void k_softmax(const float* __restrict__ part,
                                                 ushort_t* __restrict__ attn) {
    int row = blockIdx.x * 8 + (threadIdx.x >> 5);  // 0..3199
    int b = row / 200, r = row - b * 200;
    int p = threadIdx.x & 31;
    const float* p0 = part + ((size_t)b * 224 + r) * 224;
    const float* p1 = p0 + (size_t)16 * 224 * 224;
    const float scale = 0.022097086912079608f;  // 1/sqrt(2048)
    float ev[7];
    float mx = -1e30f;
#pragma unroll
    for (int j = 0; j < 7; j++) {
        int c = p * 7 + j;
        float v = (c < 200) ? (p0[c] + p1[c]) * scale : -1e30f;
        ev[j] = v;
        mx = fmaxf(mx, v);
    }
#pragma unroll
    for (int m = 1; m < 32; m <<= 1) mx = fmaxf(mx, __shfl_xor(mx, m, 32));
    float s = 0.f;
#pragma unroll
    for (int j = 0; j < 7; j++) {
        float e = __expf(ev[j] - mx);
        ev[j] = e;
        s += e;
    }
#pragma unroll
    for (int m = 1; m < 32; m <<= 1) s += __shfl_xor(s, m, 32);
    float rs = 1.0f / s;
    ushort_t* arow = attn + (size_t)row * 224;
#pragma unroll
    for (int j = 0; j < 7; j++) {
        int c = p * 7 + j;
        arow[c] = (c < 200) ? f2bf(ev[j] * rs) : (ushort_t)0;
    }
}

// ---------------- out[b][m][n] = attn[b][m][:] @ lv  (via lvT), fp32 out
__global__ __launch_bounds__(256) void k_pv(const ushort_t* __restrict__ attn,
                                            const ushort_t* __restrict__ lvT,
                                            float* __restrict__ out) {
    int nt = blockIdx.x;  // 0..15 (128 cols each)
    int qt = blockIdx.y;  // 0..12 (16 rows each)
    int b = blockIdx.z;
    int tid = threadIdx.x, lane = tid & 63, w = tid >> 6;
    int quad = lane >> 4, col = lane & 15;
    int aq = qt * 16 + col; if (aq > 199) aq = 199;
    const ushort_t* arow = attn + (size_t)(b * 200 + aq) * 224;
    int nbase = nt * 128 + w * 32;
    const ushort_t* bp0 = lvT + ((size_t)b * 2048 + nbase + col) * 224;
    const ushort_t* bp1 = lvT + ((size_t)b * 2048 + nbase + 16 + col) * 224;
    floatx4 acc[2] = {};
#pragma unroll
    for (int k0 = 0; k0 < 224; k0 += 32) {
        int ko = k0 + quad * 8;
        bf16x8 av = *(const bf16x8*)(arow + ko);
        bf16x8 b0 = *(const bf16x8*)(bp0 + ko);
        bf16x8 b1 = *(const bf16x8*)(bp1 + ko);
        acc[0] = mfma16(av, b0, acc[0]);
        acc[1] = mfma16(av, b1, acc[1]);
    }
#pragma unroll
    for (int f = 0; f < 2; f++) {
        int n = nbase + f * 16 + col;
#pragma unroll
        for (int r = 0; r < 4; r++) {
            int m = qt * 16 + quad * 4 + r;
            if (m < 200) out[(size_t)(b * 200 + m) * 2048 + n] = acc[f][r];
        }
    }
}

extern "C" void kernel_launch(void* const* d_in, const int* in_sizes, int n_in,
                              void* d_out, int out_size, void* d_ws, size_t ws_size,
                              hipStream_t stream) {
    (void)in_sizes; (void)n_in; (void)out_size; (void)ws_size;
    const float* q    = (const float*)d_in[0];
    const float* k    = (const float*)d_in[1];
    const float* v    = (const float*)d_in[2];
    const float* loc  = (const float*)d_in[3];
    const float* Wq   = (const float*)d_in[4];
    const float* bq   = (const float*)d_in[5];
    const float* Wk   = (const float*)d_in[6];
    const float* bk   = (const float*)d_in[7];
    const float* Wv   = (const float*)d_in[8];
    const float* bv   = (const float*)d_in[9];
    const float* Wloc = (const float*)d_in[10];
    const float* bloc = (const float*)d_in[11];
    const float* Wlk  = (const float*)d_in[12];
    const float* blk  = (const float*)d_in[13];
    const float* param = (const float*)d_in[14];
    float* out = (float*)d_out;

    size_t off = 0;
    auto nxt = [&](size_t bytes) {
        void* p = (char*)d_ws + off;
        off += (bytes + 255) & ~(size_t)255;
        return p;
    };
    ushort_t* wt[5];
    for (int i = 0; i < 5; i++) wt[i] = (ushort_t*)nxt(2048ull * 2048 * 2);
    ushort_t* qb    = (ushort_t*)nxt(3200ull * 2048 * 2);
    ushort_t* kb    = (ushort_t*)nxt(3200ull * 2048 * 2);
    ushort_t* vb    = (ushort_t*)nxt(3200ull * 2048 * 2);
    ushort_t* locb  = (ushort_t*)nxt(3200ull * 2048 * 2);
    ushort_t* lqp   = (ushort_t*)nxt(3200ull * 2048 * 2);
    ushort_t* llocp = (ushort_t*)nxt(3200ull * 2048 * 2);
    ushort_t* lvp   = (ushort_t*)nxt(3200ull * 2048 * 2);
    ushort_t* kcat  = (ushort_t*)nxt(16ull * 224 * 4096 * 2);
    // overlays (wt region = 41.9 MB, dead after k_gemm):
    ushort_t* lvT  = wt[0];                               // bytes 0 .. 14.7 MB
    ushort_t* attn = wt[0] + 16ull * 2048 * 224;          // 14.7 .. 16.1 MB
    float*    part = (float*)((char*)d_ws + 2ull * 2048 * 2048 * 2);  // 16.8 .. 23.2 MB (wt[2]+)
    ushort_t* qcat = qb;   // 29.4 MB into 52.4 MB conv region

    k_convert<<<dim3(6400, 4), 256, 0, stream>>>(q, k, v, loc, qb, kb, vb, locb);
    k_wtrans<<<dim3(64, 64, 5), 256, 0, stream>>>(Wq, Wk, Wv, Wloc, Wlk,
                                                  wt[0], wt[1], wt[2], wt[3], wt[4]);
    // 13 m-tiles x 8 n-tiles x 5 z = 520 blocks (8 XCDs x 65). M padded to 3328:
    // out-of-range rows read into the adjacent workspace buffer (in-bounds garbage),
    // stores are guarded by m < 3200.
    k_gemm<<<dim3(520), 512, 0, stream>>>(qb, kb, vb, locb, locb,
                                          wt[0], wt[1], wt[2], wt[3], wt[4],
                                          bq, bk, bv, bloc, blk,
                                          lqp, lvp, llocp, kcat);
    k_qprep<<<dim3(3200), 256, 0, stream>>>(lqp, llocp, param, qcat);
    k_vtrans<<<dim3(64, 7, 16), 256, 0, stream>>>(lvp, lvT);
    k_scores<<<dim3(7, 16, 2), 256, 0, stream>>>(qcat, kcat, part);
    k_softmax<<<dim3(400), 256, 0, stream>>>(part, attn);
    k_pv<<<dim3(16, 13, 16), 256, 0, stream>>>(attn, lvT, out);
}